// Round 1
// baseline (412.456 us; speedup 1.0000x reference)
//
#include <hip/hip_runtime.h>
#include <math.h>

// Problem constants (from reference setup_inputs)
#define B_IMG   8
#define A_ANCH  100000
#define M_ANN   32
#define C_CLS   80
#define TILE    256          // anchors per block
#define NTHREADS 256
#define NWAVES  (NTHREADS/64)

// ---------------------------------------------------------------------------
// ws layout: per image b: ws[b*3+0]=cls_loss_sum, ws[b*3+1]=reg_loss_sum,
//            ws[b*3+2]=num_pos.  Re-poisoned each launch -> zero it first.
// ---------------------------------------------------------------------------
__global__ void focal_init(float* __restrict__ ws) {
    int i = threadIdx.x;
    if (i < 3 * B_IMG) ws[i] = 0.0f;
}

__global__ __launch_bounds__(NTHREADS)
void focal_main(const float* __restrict__ cls,      // [B,A,C]
                const float* __restrict__ regr,     // [B,A,4]
                const float* __restrict__ anchors,  // [1,A,4]
                const float* __restrict__ ann,      // [B,M,6]
                float* __restrict__ ws)             // [B,3]
{
    __shared__ float s_ann[M_ANN][6];
    __shared__ float s_area[M_ANN];
    __shared__ int   s_code[TILE];   // >=0: pos w/ class k; -2: neg; -1: ignore
    __shared__ float s_red[3][NWAVES];

    const int b  = blockIdx.y;
    const int a0 = blockIdx.x * TILE;
    const int t  = threadIdx.x;

    // --- stage annotations for this image ---
    if (t < M_ANN * 6) ((float*)s_ann)[t] = ann[(size_t)b * M_ANN * 6 + t];
    __syncthreads();
    if (t < M_ANN)
        s_area[t] = (s_ann[t][2] - s_ann[t][0]) * (s_ann[t][3] - s_ann[t][1]);
    __syncthreads();

    float reg_acc = 0.0f;
    float pos_cnt = 0.0f;

    // --- phase 1: one thread per anchor -> IoU argmax, code, reg loss ---
    const int a = a0 + t;
    if (a < A_ANCH) {
        const float4 ab = ((const float4*)anchors)[a];
        const float aw = ab.z - ab.x;
        const float ah = ab.w - ab.y;
        const float acx = ab.x + 0.5f * aw;
        const float acy = ab.y + 0.5f * ah;
        const float area_a = aw * ah;

        float best = -2.0f;
        int   bm   = 0;
        #pragma unroll 8
        for (int m = 0; m < M_ANN; ++m) {
            float iou;
            if (s_ann[m][4] == -1.0f) {
                iou = -1.0f;                       // padding mask
            } else {
                float iw = fminf(ab.z, s_ann[m][2]) - fmaxf(ab.x, s_ann[m][0]);
                float ih = fminf(ab.w, s_ann[m][3]) - fmaxf(ab.y, s_ann[m][1]);
                float inter = fmaxf(iw, 0.0f) * fmaxf(ih, 0.0f);
                float ua = fmaxf(area_a + s_area[m] - inter, 1e-8f);
                iou = inter / ua;
            }
            if (iou > best) { best = iou; bm = m; } // strict '>' keeps first max (JAX argmax)
        }

        const bool pos = (best >= 0.5f);
        int code;
        if (pos)                 code = (int)s_ann[bm][4];
        else if (best < 0.4f)    code = -2;
        else                     code = -1;
        s_code[t] = code;

        if (pos) {
            pos_cnt = 1.0f;
            // regression targets (centers from unclamped w/h, clamp for log)
            const float gx1 = s_ann[bm][0], gy1 = s_ann[bm][1];
            const float gx2 = s_ann[bm][2], gy2 = s_ann[bm][3];
            float gw = gx2 - gx1, gh = gy2 - gy1;
            const float gcx = gx1 + 0.5f * gw;
            const float gcy = gy1 + 0.5f * gh;
            gw = fmaxf(gw, 1.0f); gh = fmaxf(gh, 1.0f);
            const float t0 = (gcx - acx) / aw * 10.0f;   // /0.1
            const float t1v = (gcy - acy) / ah * 10.0f;
            const float t2 = logf(gw / aw) * 5.0f;       // /0.2
            const float t3 = logf(gh / ah) * 5.0f;

            const float4 rg = ((const float4*)regr)[(size_t)b * A_ANCH + a];
            const float d0 = fabsf(t0  - rg.x);
            const float d1 = fabsf(t1v - rg.y);
            const float d2 = fabsf(t2  - rg.z);
            const float d3 = fabsf(t3  - rg.w);
            const float th = 1.0f / 9.0f;
            const float c_ = 0.5f / 9.0f;
            reg_acc += (d0 <= th) ? 4.5f * d0 * d0 : d0 - c_;
            reg_acc += (d1 <= th) ? 4.5f * d1 * d1 : d1 - c_;
            reg_acc += (d2 <= th) ? 4.5f * d2 * d2 : d2 - c_;
            reg_acc += (d3 <= th) ? 4.5f * d3 * d3 : d3 - c_;
        }
    } else {
        s_code[t] = -1;   // out-of-range anchors contribute nothing
    }
    __syncthreads();

    // --- phase 2: coalesced float4 sweep over this block's [n_anch x C] slab ---
    float cls_acc = 0.0f;
    const int n_anch = min(TILE, A_ANCH - a0);
    const int nv = n_anch * (C_CLS / 4);   // float4 count
    const float4* cbase = (const float4*)(cls + ((size_t)b * A_ANCH + a0) * C_CLS);

    for (int v = t; v < nv; v += NTHREADS) {
        const int al = v / (C_CLS / 4);          // local anchor
        const int code = s_code[al];
        if (code == -1) continue;                 // ignore band: skip load entirely
        const int c0 = (v % (C_CLS / 4)) * 4;
        const float4 p4 = cbase[v];
        const float pv[4] = {p4.x, p4.y, p4.z, p4.w};
        #pragma unroll
        for (int j = 0; j < 4; ++j) {
            const float p = fminf(fmaxf(pv[j], 1e-4f), 1.0f - 1e-4f);
            const bool tgt1 = (code == c0 + j);   // false for code==-2 (all-neg)
            const float q = tgt1 ? (1.0f - p) : p;     // (1-p) if target==1 else p
            const float w = (tgt1 ? 0.25f : 0.75f) * q * q;
            // bce: t==1 -> -log(p) = -log(1-q); t==0 -> -log(1-p) = -log(1-q)
            cls_acc += w * (-__logf(1.0f - q));
        }
    }

    // --- block reduction (wave shuffle then LDS) ---
    #pragma unroll
    for (int off = 32; off > 0; off >>= 1) {
        cls_acc += __shfl_down(cls_acc, off, 64);
        reg_acc += __shfl_down(reg_acc, off, 64);
        pos_cnt += __shfl_down(pos_cnt, off, 64);
    }
    const int wave = t >> 6, lane = t & 63;
    if (lane == 0) {
        s_red[0][wave] = cls_acc;
        s_red[1][wave] = reg_acc;
        s_red[2][wave] = pos_cnt;
    }
    __syncthreads();
    if (t == 0) {
        float c = 0.f, r = 0.f, p = 0.f;
        #pragma unroll
        for (int w = 0; w < NWAVES; ++w) { c += s_red[0][w]; r += s_red[1][w]; p += s_red[2][w]; }
        atomicAdd(&ws[b * 3 + 0], c);
        atomicAdd(&ws[b * 3 + 1], r);
        atomicAdd(&ws[b * 3 + 2], p);
    }
}

__global__ void focal_final(const float* __restrict__ ws, float* __restrict__ out) {
    if (threadIdx.x == 0) {
        float cl = 0.f, rl = 0.f;
        for (int b = 0; b < B_IMG; ++b) {
            const float np  = ws[b * 3 + 2];
            const float mnp = fmaxf(np, 1.0f);
            cl += ws[b * 3 + 0] / mnp;
            rl += (np > 0.0f) ? ws[b * 3 + 1] / (4.0f * mnp) : 0.0f;
        }
        out[0] = cl / (float)B_IMG;
        out[1] = rl / (float)B_IMG;
    }
}

extern "C" void kernel_launch(void* const* d_in, const int* in_sizes, int n_in,
                              void* d_out, int out_size, void* d_ws, size_t ws_size,
                              hipStream_t stream) {
    const float* cls     = (const float*)d_in[0];  // [B,A,C]
    const float* regr    = (const float*)d_in[1];  // [B,A,4]
    const float* anchors = (const float*)d_in[2];  // [1,A,4]
    const float* ann     = (const float*)d_in[3];  // [B,M,6]
    float* out = (float*)d_out;
    float* ws  = (float*)d_ws;

    focal_init<<<1, 64, 0, stream>>>(ws);

    dim3 grid((A_ANCH + TILE - 1) / TILE, B_IMG);
    focal_main<<<grid, NTHREADS, 0, stream>>>(cls, regr, anchors, ann, ws);

    focal_final<<<1, 64, 0, stream>>>(ws, out);
}

// Round 2
// 406.367 us; speedup vs baseline: 1.0150x; 1.0150x over previous
//
#include <hip/hip_runtime.h>
#include <math.h>

// Problem constants (from reference setup_inputs)
#define B_IMG   8
#define A_ANCH  100000
#define M_ANN   32
#define C_CLS   80
#define TILE    256          // anchors per block
#define NTHREADS 256
#define NWAVES  (NTHREADS/64)
#define V_PER_ANCH (C_CLS/4) // 20 float4 per anchor row

// ws layout: per image b: ws[b*3+0]=cls_loss_sum, ws[b*3+1]=reg_loss_sum,
//            ws[b*3+2]=num_pos.  Re-poisoned each launch -> zero it first.
__global__ void focal_init(float* __restrict__ ws) {
    int i = threadIdx.x;
    if (i < 3 * B_IMG) ws[i] = 0.0f;
}

// branch-free per-float4 focal term; mask handles ignore band
__device__ __forceinline__ float focal4(float4 p4, int code, int c0) {
    const float m = (code != -1) ? 1.0f : 0.0f;
    float acc = 0.0f;
    const float pv[4] = {p4.x, p4.y, p4.z, p4.w};
    #pragma unroll
    for (int j = 0; j < 4; ++j) {
        const float p = fminf(fmaxf(pv[j], 1e-4f), 1.0f - 1e-4f);
        const bool t1 = (code == c0 + j);
        const float q = t1 ? (1.0f - p) : p;          // (1-p) if target==1 else p
        const float w = t1 ? 0.25f : 0.75f;           // alpha factor
        // bce both cases collapse to -log(1-q)
        acc = fmaf(m * w * q * q, -__logf(1.0f - q), acc);
    }
    return acc;
}

__global__ __launch_bounds__(NTHREADS)
void focal_main(const float* __restrict__ cls,      // [B,A,C]
                const float* __restrict__ regr,     // [B,A,4]
                const float* __restrict__ anchors,  // [1,A,4]
                const float* __restrict__ ann,      // [B,M,6]
                float* __restrict__ ws)             // [B,3]
{
    __shared__ float s_ann[M_ANN][6];
    __shared__ float s_area[M_ANN];
    __shared__ int   s_code[TILE];   // >=0: pos w/ class k; -2: neg; -1: ignore
    __shared__ float s_red[3][NWAVES];

    const int b  = blockIdx.y;
    const int a0 = blockIdx.x * TILE;
    const int t  = threadIdx.x;

    // --- stage annotations for this image ---
    if (t < M_ANN * 6) ((float*)s_ann)[t] = ann[(size_t)b * M_ANN * 6 + t];
    __syncthreads();
    if (t < M_ANN)
        s_area[t] = (s_ann[t][2] - s_ann[t][0]) * (s_ann[t][3] - s_ann[t][1]);
    __syncthreads();

    float reg_acc = 0.0f;
    float pos_cnt = 0.0f;

    // --- phase 1: one thread per anchor -> IoU argmax, code, reg loss ---
    const int a = a0 + t;
    if (a < A_ANCH) {
        const float4 ab = ((const float4*)anchors)[a];
        const float aw = ab.z - ab.x;
        const float ah = ab.w - ab.y;
        const float acx = ab.x + 0.5f * aw;
        const float acy = ab.y + 0.5f * ah;
        const float area_a = aw * ah;

        float best = -2.0f;
        int   bm   = 0;
        #pragma unroll 8
        for (int m = 0; m < M_ANN; ++m) {
            float iou;
            if (s_ann[m][4] == -1.0f) {
                iou = -1.0f;                       // padding mask
            } else {
                float iw = fminf(ab.z, s_ann[m][2]) - fmaxf(ab.x, s_ann[m][0]);
                float ih = fminf(ab.w, s_ann[m][3]) - fmaxf(ab.y, s_ann[m][1]);
                float inter = fmaxf(iw, 0.0f) * fmaxf(ih, 0.0f);
                float ua = fmaxf(area_a + s_area[m] - inter, 1e-8f);
                iou = inter / ua;
            }
            if (iou > best) { best = iou; bm = m; } // strict '>' keeps first max (JAX argmax)
        }

        const bool pos = (best >= 0.5f);
        int code;
        if (pos)                 code = (int)s_ann[bm][4];
        else if (best < 0.4f)    code = -2;
        else                     code = -1;
        s_code[t] = code;

        if (pos) {
            pos_cnt = 1.0f;
            const float gx1 = s_ann[bm][0], gy1 = s_ann[bm][1];
            const float gx2 = s_ann[bm][2], gy2 = s_ann[bm][3];
            float gw = gx2 - gx1, gh = gy2 - gy1;
            const float gcx = gx1 + 0.5f * gw;
            const float gcy = gy1 + 0.5f * gh;
            gw = fmaxf(gw, 1.0f); gh = fmaxf(gh, 1.0f);
            const float t0 = (gcx - acx) / aw * 10.0f;   // /0.1
            const float t1v = (gcy - acy) / ah * 10.0f;
            const float t2 = logf(gw / aw) * 5.0f;       // /0.2
            const float t3 = logf(gh / ah) * 5.0f;

            const float4 rg = ((const float4*)regr)[(size_t)b * A_ANCH + a];
            const float d0 = fabsf(t0  - rg.x);
            const float d1 = fabsf(t1v - rg.y);
            const float d2 = fabsf(t2  - rg.z);
            const float d3 = fabsf(t3  - rg.w);
            const float th = 1.0f / 9.0f;
            const float c_ = 0.5f / 9.0f;
            reg_acc += (d0 <= th) ? 4.5f * d0 * d0 : d0 - c_;
            reg_acc += (d1 <= th) ? 4.5f * d1 * d1 : d1 - c_;
            reg_acc += (d2 <= th) ? 4.5f * d2 * d2 : d2 - c_;
            reg_acc += (d3 <= th) ? 4.5f * d3 * d3 : d3 - c_;
        }
    } else {
        s_code[t] = -1;   // out-of-range anchors contribute nothing
    }
    __syncthreads();

    // --- phase 2: coalesced branch-free float4 sweep, 5-deep load batching ---
    float cls_acc = 0.0f;
    const int n_anch = min(TILE, A_ANCH - a0);
    const float4* cbase = (const float4*)(cls + ((size_t)b * A_ANCH + a0) * C_CLS);

    if (n_anch == TILE) {
        // full tile: exactly 20 float4 per thread; 4 chunks x 5 batched loads
        #pragma unroll
        for (int kk = 0; kk < 4; ++kk) {
            float4 r[5];
            int    vv[5];
            #pragma unroll
            for (int u = 0; u < 5; ++u) {
                vv[u] = t + (kk * 5 + u) * NTHREADS;
                r[u]  = cbase[vv[u]];
            }
            #pragma unroll
            for (int u = 0; u < 5; ++u) {
                const int v  = vv[u];
                const int al = v / V_PER_ANCH;
                const int c0 = (v - al * V_PER_ANCH) * 4;
                cls_acc += focal4(r[u], s_code[al], c0);
            }
        }
    } else {
        // edge tile (8 of 3128 blocks)
        const int nv = n_anch * V_PER_ANCH;
        for (int v = t; v < nv; v += NTHREADS) {
            const int al = v / V_PER_ANCH;
            const int c0 = (v - al * V_PER_ANCH) * 4;
            cls_acc += focal4(cbase[v], s_code[al], c0);
        }
    }

    // --- block reduction (wave shuffle then LDS) ---
    #pragma unroll
    for (int off = 32; off > 0; off >>= 1) {
        cls_acc += __shfl_down(cls_acc, off, 64);
        reg_acc += __shfl_down(reg_acc, off, 64);
        pos_cnt += __shfl_down(pos_cnt, off, 64);
    }
    const int wave = t >> 6, lane = t & 63;
    if (lane == 0) {
        s_red[0][wave] = cls_acc;
        s_red[1][wave] = reg_acc;
        s_red[2][wave] = pos_cnt;
    }
    __syncthreads();
    if (t == 0) {
        float c = 0.f, r = 0.f, p = 0.f;
        #pragma unroll
        for (int w = 0; w < NWAVES; ++w) { c += s_red[0][w]; r += s_red[1][w]; p += s_red[2][w]; }
        atomicAdd(&ws[b * 3 + 0], c);
        atomicAdd(&ws[b * 3 + 1], r);
        atomicAdd(&ws[b * 3 + 2], p);
    }
}

__global__ void focal_final(const float* __restrict__ ws, float* __restrict__ out) {
    if (threadIdx.x == 0) {
        float cl = 0.f, rl = 0.f;
        for (int b = 0; b < B_IMG; ++b) {
            const float np  = ws[b * 3 + 2];
            const float mnp = fmaxf(np, 1.0f);
            cl += ws[b * 3 + 0] / mnp;
            rl += (np > 0.0f) ? ws[b * 3 + 1] / (4.0f * mnp) : 0.0f;
        }
        out[0] = cl / (float)B_IMG;
        out[1] = rl / (float)B_IMG;
    }
}

extern "C" void kernel_launch(void* const* d_in, const int* in_sizes, int n_in,
                              void* d_out, int out_size, void* d_ws, size_t ws_size,
                              hipStream_t stream) {
    const float* cls     = (const float*)d_in[0];  // [B,A,C]
    const float* regr    = (const float*)d_in[1];  // [B,A,4]
    const float* anchors = (const float*)d_in[2];  // [1,A,4]
    const float* ann     = (const float*)d_in[3];  // [B,M,6]
    float* out = (float*)d_out;
    float* ws  = (float*)d_ws;

    focal_init<<<1, 64, 0, stream>>>(ws);

    dim3 grid((A_ANCH + TILE - 1) / TILE, B_IMG);
    focal_main<<<grid, NTHREADS, 0, stream>>>(cls, regr, anchors, ann, ws);

    focal_final<<<1, 64, 0, stream>>>(ws, out);
}

// Round 3
// 398.540 us; speedup vs baseline: 1.0349x; 1.0196x over previous
//
#include <hip/hip_runtime.h>
#include <math.h>

// Problem constants (from reference setup_inputs)
#define B_IMG   8
#define A_ANCH  100000
#define M_ANN   32
#define C_CLS   80
#define TILE    256          // anchors per block
#define NTHREADS 256
#define NWAVES  (NTHREADS/64)
#define V_PER_ANCH (C_CLS/4) // 20 float4 per anchor row

// staging: block slab = TILE*20 float4 = 5120 float4 = 80 KB
#define CHUNK_F4   1024      // 16 KB per chunk
#define NITER      5         // 5120 / 1024
#define F4_PER_THR 4         // 1024 / 256

// ws layout: per image b: ws[b*3+0]=cls_loss_sum, ws[b*3+1]=reg_loss_sum,
//            ws[b*3+2]=num_pos.  Re-poisoned each launch -> zero it first.
__global__ void focal_init(float* __restrict__ ws) {
    int i = threadIdx.x;
    if (i < 3 * B_IMG) ws[i] = 0.0f;
}

// branch-free per-float4 focal term; mask handles ignore band
__device__ __forceinline__ float focal4(float4 p4, int code, int c0) {
    const float m = (code != -1) ? 1.0f : 0.0f;
    float acc = 0.0f;
    const float pv[4] = {p4.x, p4.y, p4.z, p4.w};
    #pragma unroll
    for (int j = 0; j < 4; ++j) {
        const float p = fminf(fmaxf(pv[j], 1e-4f), 1.0f - 1e-4f);
        const bool t1 = (code == c0 + j);
        const float q = t1 ? (1.0f - p) : p;          // (1-p) if target==1 else p
        const float w = t1 ? 0.25f : 0.75f;           // alpha factor
        // bce both cases collapse to -log(1-q)
        acc = fmaf(m * w * q * q, -__logf(1.0f - q), acc);
    }
    return acc;
}

__global__ __launch_bounds__(NTHREADS)
void focal_main(const float* __restrict__ cls,      // [B,A,C]
                const float* __restrict__ regr,     // [B,A,4]
                const float* __restrict__ anchors,  // [1,A,4]
                const float* __restrict__ ann,      // [B,M,6]
                float* __restrict__ ws)             // [B,3]
{
    __shared__ float  s_ann[M_ANN][6];
    __shared__ float  s_area[M_ANN];
    __shared__ int    s_code[TILE];   // >=0: pos class; -2: neg; -1: ignore
    __shared__ float  s_red[3][NWAVES];
    __shared__ float4 s_stage[2][CHUNK_F4];   // 2 x 16 KB double buffer

    const int b    = blockIdx.y;
    const int a0   = blockIdx.x * TILE;
    const int t    = threadIdx.x;
    const int wave = t >> 6;
    const int lane = t & 63;

    const int n_anch = min(TILE, A_ANCH - a0);
    const bool full  = (n_anch == TILE);
    const float4* cbase = (const float4*)(cls + ((size_t)b * A_ANCH + a0) * C_CLS);

    // --- stage annotations for this image ---
    if (t < M_ANN * 6) ((float*)s_ann)[t] = ann[(size_t)b * M_ANN * 6 + t];
    __syncthreads();
    if (t < M_ANN)
        s_area[t] = (s_ann[t][2] - s_ann[t][0]) * (s_ann[t][3] - s_ann[t][1]);

    // --- prefetch chunk 0 into buffer 0 (async, direct-to-LDS) ---
    // LDS dest is wave-uniform base; HW lands lane i at base + i*16.
    // Global src for lane i = chunk base + uniform_off + i*16 -> linear copy.
    auto issue_chunk = [&](int c, int p) {
        const char* gch = (const char*)cbase + (size_t)c * (CHUNK_F4 * 16);
        #pragma unroll
        for (int u = 0; u < F4_PER_THR; ++u) {
            const int off = __builtin_amdgcn_readfirstlane((wave * F4_PER_THR + u) * 1024);
            const char* src = gch + off + lane * 16;
            char* dst = (char*)&s_stage[p][0] + off;
            __builtin_amdgcn_global_load_lds(
                (const __attribute__((address_space(1))) void*)src,
                (__attribute__((address_space(3))) void*)dst,
                16, 0, 0);
        }
    };
    if (full) issue_chunk(0, 0);

    float reg_acc = 0.0f;
    float pos_cnt = 0.0f;

    // --- phase 1: one thread per anchor -> IoU argmax, code, reg loss ---
    // (overlaps with chunk-0 loads in flight)
    const int a = a0 + t;
    if (a < A_ANCH) {
        const float4 ab = ((const float4*)anchors)[a];
        const float aw = ab.z - ab.x;
        const float ah = ab.w - ab.y;
        const float acx = ab.x + 0.5f * aw;
        const float acy = ab.y + 0.5f * ah;
        const float area_a = aw * ah;

        float best = -2.0f;
        int   bm   = 0;
        #pragma unroll 8
        for (int m = 0; m < M_ANN; ++m) {
            float iou;
            if (s_ann[m][4] == -1.0f) {
                iou = -1.0f;                       // padding mask
            } else {
                float iw = fminf(ab.z, s_ann[m][2]) - fmaxf(ab.x, s_ann[m][0]);
                float ih = fminf(ab.w, s_ann[m][3]) - fmaxf(ab.y, s_ann[m][1]);
                float inter = fmaxf(iw, 0.0f) * fmaxf(ih, 0.0f);
                float ua = fmaxf(area_a + s_area[m] - inter, 1e-8f);
                iou = inter / ua;
            }
            if (iou > best) { best = iou; bm = m; } // strict '>' = first max (JAX argmax)
        }

        const bool pos = (best >= 0.5f);
        int code;
        if (pos)                 code = (int)s_ann[bm][4];
        else if (best < 0.4f)    code = -2;
        else                     code = -1;
        s_code[t] = code;

        if (pos) {
            pos_cnt = 1.0f;
            const float gx1 = s_ann[bm][0], gy1 = s_ann[bm][1];
            const float gx2 = s_ann[bm][2], gy2 = s_ann[bm][3];
            float gw = gx2 - gx1, gh = gy2 - gy1;
            const float gcx = gx1 + 0.5f * gw;
            const float gcy = gy1 + 0.5f * gh;
            gw = fmaxf(gw, 1.0f); gh = fmaxf(gh, 1.0f);
            const float t0 = (gcx - acx) / aw * 10.0f;   // /0.1
            const float t1v = (gcy - acy) / ah * 10.0f;
            const float t2 = logf(gw / aw) * 5.0f;       // /0.2
            const float t3 = logf(gh / ah) * 5.0f;

            const float4 rg = ((const float4*)regr)[(size_t)b * A_ANCH + a];
            const float d0 = fabsf(t0  - rg.x);
            const float d1 = fabsf(t1v - rg.y);
            const float d2 = fabsf(t2  - rg.z);
            const float d3 = fabsf(t3  - rg.w);
            const float th = 1.0f / 9.0f;
            const float c_ = 0.5f / 9.0f;
            reg_acc += (d0 <= th) ? 4.5f * d0 * d0 : d0 - c_;
            reg_acc += (d1 <= th) ? 4.5f * d1 * d1 : d1 - c_;
            reg_acc += (d2 <= th) ? 4.5f * d2 * d2 : d2 - c_;
            reg_acc += (d3 <= th) ? 4.5f * d3 * d3 : d3 - c_;
        }
    } else {
        s_code[t] = -1;
    }
    __syncthreads();   // publishes s_code; drains chunk-0 loads (they had phase 1 to land)

    // --- phase 2: double-buffered LDS-staged sweep ---
    float cls_acc = 0.0f;
    if (full) {
        #pragma unroll
        for (int it = 0; it < NITER; ++it) {
            const int p = it & 1;
            if (it + 1 < NITER) issue_chunk(it + 1, p ^ 1);   // async, overlaps consume below
            #pragma unroll
            for (int u = 0; u < F4_PER_THR; ++u) {
                const int idx = t + u * NTHREADS;
                const float4 p4 = s_stage[p][idx];
                const int v  = it * CHUNK_F4 + idx;
                const int al = v / V_PER_ANCH;
                const int c0 = (v - al * V_PER_ANCH) * 4;
                cls_acc += focal4(p4, s_code[al], c0);
            }
            if (it + 1 < NITER) __syncthreads();  // drain it+1 loads; protect buffer reuse
        }
    } else {
        // edge tile (8 of 3128 blocks): simple path
        const int nv = n_anch * V_PER_ANCH;
        for (int v = t; v < nv; v += NTHREADS) {
            const int al = v / V_PER_ANCH;
            const int c0 = (v - al * V_PER_ANCH) * 4;
            cls_acc += focal4(cbase[v], s_code[al], c0);
        }
    }

    // --- block reduction (wave shuffle then LDS) ---
    #pragma unroll
    for (int off = 32; off > 0; off >>= 1) {
        cls_acc += __shfl_down(cls_acc, off, 64);
        reg_acc += __shfl_down(reg_acc, off, 64);
        pos_cnt += __shfl_down(pos_cnt, off, 64);
    }
    if (lane == 0) {
        s_red[0][wave] = cls_acc;
        s_red[1][wave] = reg_acc;
        s_red[2][wave] = pos_cnt;
    }
    __syncthreads();
    if (t == 0) {
        float c = 0.f, r = 0.f, p = 0.f;
        #pragma unroll
        for (int w = 0; w < NWAVES; ++w) { c += s_red[0][w]; r += s_red[1][w]; p += s_red[2][w]; }
        atomicAdd(&ws[b * 3 + 0], c);
        atomicAdd(&ws[b * 3 + 1], r);
        atomicAdd(&ws[b * 3 + 2], p);
    }
}

__global__ void focal_final(const float* __restrict__ ws, float* __restrict__ out) {
    if (threadIdx.x == 0) {
        float cl = 0.f, rl = 0.f;
        for (int b = 0; b < B_IMG; ++b) {
            const float np  = ws[b * 3 + 2];
            const float mnp = fmaxf(np, 1.0f);
            cl += ws[b * 3 + 0] / mnp;
            rl += (np > 0.0f) ? ws[b * 3 + 1] / (4.0f * mnp) : 0.0f;
        }
        out[0] = cl / (float)B_IMG;
        out[1] = rl / (float)B_IMG;
    }
}

extern "C" void kernel_launch(void* const* d_in, const int* in_sizes, int n_in,
                              void* d_out, int out_size, void* d_ws, size_t ws_size,
                              hipStream_t stream) {
    const float* cls     = (const float*)d_in[0];  // [B,A,C]
    const float* regr    = (const float*)d_in[1];  // [B,A,4]
    const float* anchors = (const float*)d_in[2];  // [1,A,4]
    const float* ann     = (const float*)d_in[3];  // [B,M,6]
    float* out = (float*)d_out;
    float* ws  = (float*)d_ws;

    focal_init<<<1, 64, 0, stream>>>(ws);

    dim3 grid((A_ANCH + TILE - 1) / TILE, B_IMG);
    focal_main<<<grid, NTHREADS, 0, stream>>>(cls, regr, anchors, ann, ws);

    focal_final<<<1, 64, 0, stream>>>(ws, out);
}

// Round 4
// 369.947 us; speedup vs baseline: 1.1149x; 1.0773x over previous
//
#include <hip/hip_runtime.h>
#include <math.h>

// Problem constants (from reference setup_inputs)
#define B_IMG   8
#define A_ANCH  100000
#define M_ANN   32
#define C_CLS   80
#define TILE    256          // anchors per block
#define NTHREADS 256
#define NWAVES  (NTHREADS/64)
#define V_PER_ANCH (C_CLS/4) // 20 float4 per anchor row
#define NBLK_X  ((A_ANCH + TILE - 1) / TILE)   // 391 blocks per image
#define PLANE   3200                            // padded plane stride (floats)

// ws layout (floats): plane 0 = cls partials, plane 1 = reg partials,
// plane 2 = num_pos partials; index = b*NBLK_X + blockIdx.x.
// Every slot is written unconditionally -> no zero-init kernel needed.

// branch-free per-float4 focal term; mask handles ignore band
__device__ __forceinline__ float focal4(float4 p4, int code, int c0) {
    const float m = (code != -1) ? 1.0f : 0.0f;
    float acc = 0.0f;
    const float pv[4] = {p4.x, p4.y, p4.z, p4.w};
    #pragma unroll
    for (int j = 0; j < 4; ++j) {
        const float p = fminf(fmaxf(pv[j], 1e-4f), 1.0f - 1e-4f);
        const bool t1 = (code == c0 + j);
        const float q = t1 ? (1.0f - p) : p;          // (1-p) if target==1 else p
        const float w = t1 ? 0.25f : 0.75f;           // alpha factor
        // bce both cases collapse to -log(1-q)
        acc = fmaf(m * w * q * q, -__logf(1.0f - q), acc);
    }
    return acc;
}

__global__ __launch_bounds__(NTHREADS)
void focal_main(const float* __restrict__ cls,      // [B,A,C]
                const float* __restrict__ regr,     // [B,A,4]
                const float* __restrict__ anchors,  // [1,A,4]
                const float* __restrict__ ann,      // [B,M,6]
                float* __restrict__ part)           // [3][PLANE]
{
    __shared__ float s_ann[M_ANN][6];
    __shared__ float s_area[M_ANN];
    __shared__ int   s_code[TILE];   // >=0: pos class; -2: neg; -1: ignore
    __shared__ float s_red[3][NWAVES];

    const int b  = blockIdx.y;
    const int a0 = blockIdx.x * TILE;
    const int t  = threadIdx.x;

    // --- stage annotations for this image ---
    if (t < M_ANN * 6) ((float*)s_ann)[t] = ann[(size_t)b * M_ANN * 6 + t];
    __syncthreads();
    if (t < M_ANN)
        s_area[t] = (s_ann[t][2] - s_ann[t][0]) * (s_ann[t][3] - s_ann[t][1]);
    __syncthreads();

    float reg_acc = 0.0f;
    float pos_cnt = 0.0f;

    // --- phase 1: one thread per anchor -> IoU argmax, code, reg loss ---
    const int a = a0 + t;
    if (a < A_ANCH) {
        const float4 ab = ((const float4*)anchors)[a];
        const float aw = ab.z - ab.x;
        const float ah = ab.w - ab.y;
        const float acx = ab.x + 0.5f * aw;
        const float acy = ab.y + 0.5f * ah;
        const float area_a = aw * ah;

        float best = -2.0f;
        int   bm   = 0;
        #pragma unroll 8
        for (int m = 0; m < M_ANN; ++m) {
            float iou;
            if (s_ann[m][4] == -1.0f) {
                iou = -1.0f;                       // padding mask
            } else {
                float iw = fminf(ab.z, s_ann[m][2]) - fmaxf(ab.x, s_ann[m][0]);
                float ih = fminf(ab.w, s_ann[m][3]) - fmaxf(ab.y, s_ann[m][1]);
                float inter = fmaxf(iw, 0.0f) * fmaxf(ih, 0.0f);
                float ua = fmaxf(area_a + s_area[m] - inter, 1e-8f);
                iou = inter / ua;
            }
            if (iou > best) { best = iou; bm = m; } // strict '>' = first max (JAX argmax)
        }

        const bool pos = (best >= 0.5f);
        int code;
        if (pos)                 code = (int)s_ann[bm][4];
        else if (best < 0.4f)    code = -2;
        else                     code = -1;
        s_code[t] = code;

        if (pos) {
            pos_cnt = 1.0f;
            const float gx1 = s_ann[bm][0], gy1 = s_ann[bm][1];
            const float gx2 = s_ann[bm][2], gy2 = s_ann[bm][3];
            float gw = gx2 - gx1, gh = gy2 - gy1;
            const float gcx = gx1 + 0.5f * gw;
            const float gcy = gy1 + 0.5f * gh;
            gw = fmaxf(gw, 1.0f); gh = fmaxf(gh, 1.0f);
            const float t0 = (gcx - acx) / aw * 10.0f;   // /0.1
            const float t1v = (gcy - acy) / ah * 10.0f;
            const float t2 = logf(gw / aw) * 5.0f;       // /0.2
            const float t3 = logf(gh / ah) * 5.0f;

            const float4 rg = ((const float4*)regr)[(size_t)b * A_ANCH + a];
            const float d0 = fabsf(t0  - rg.x);
            const float d1 = fabsf(t1v - rg.y);
            const float d2 = fabsf(t2  - rg.z);
            const float d3 = fabsf(t3  - rg.w);
            const float th = 1.0f / 9.0f;
            const float c_ = 0.5f / 9.0f;
            reg_acc += (d0 <= th) ? 4.5f * d0 * d0 : d0 - c_;
            reg_acc += (d1 <= th) ? 4.5f * d1 * d1 : d1 - c_;
            reg_acc += (d2 <= th) ? 4.5f * d2 * d2 : d2 - c_;
            reg_acc += (d3 <= th) ? 4.5f * d3 * d3 : d3 - c_;
        }
    } else {
        s_code[t] = -1;
    }
    __syncthreads();

    // --- phase 2: coalesced branch-free float4 sweep, 5-deep load batching ---
    float cls_acc = 0.0f;
    const int n_anch = min(TILE, A_ANCH - a0);
    const float4* cbase = (const float4*)(cls + ((size_t)b * A_ANCH + a0) * C_CLS);

    if (n_anch == TILE) {
        #pragma unroll
        for (int kk = 0; kk < 4; ++kk) {
            float4 r[5];
            int    vv[5];
            #pragma unroll
            for (int u = 0; u < 5; ++u) {
                vv[u] = t + (kk * 5 + u) * NTHREADS;
                r[u]  = cbase[vv[u]];
            }
            #pragma unroll
            for (int u = 0; u < 5; ++u) {
                const int v  = vv[u];
                const int al = v / V_PER_ANCH;
                const int c0 = (v - al * V_PER_ANCH) * 4;
                cls_acc += focal4(r[u], s_code[al], c0);
            }
        }
    } else {
        // edge tile (8 of 3128 blocks)
        const int nv = n_anch * V_PER_ANCH;
        for (int v = t; v < nv; v += NTHREADS) {
            const int al = v / V_PER_ANCH;
            const int c0 = (v - al * V_PER_ANCH) * 4;
            cls_acc += focal4(cbase[v], s_code[al], c0);
        }
    }

    // --- block reduction (wave shuffle then LDS), then PLAIN stores ---
    #pragma unroll
    for (int off = 32; off > 0; off >>= 1) {
        cls_acc += __shfl_down(cls_acc, off, 64);
        reg_acc += __shfl_down(reg_acc, off, 64);
        pos_cnt += __shfl_down(pos_cnt, off, 64);
    }
    const int wave = t >> 6, lane = t & 63;
    if (lane == 0) {
        s_red[0][wave] = cls_acc;
        s_red[1][wave] = reg_acc;
        s_red[2][wave] = pos_cnt;
    }
    __syncthreads();
    if (t == 0) {
        float c = 0.f, r = 0.f, p = 0.f;
        #pragma unroll
        for (int w = 0; w < NWAVES; ++w) { c += s_red[0][w]; r += s_red[1][w]; p += s_red[2][w]; }
        const int idx = b * NBLK_X + blockIdx.x;   // unique slot per block: NO atomics
        part[idx]             = c;
        part[PLANE + idx]     = r;
        part[2 * PLANE + idx] = p;
    }
}

// One block: reduce 8 x 391 partials and finalize both outputs.
__global__ __launch_bounds__(256)
void focal_reduce(const float* __restrict__ part, float* __restrict__ out) {
    const int t = threadIdx.x;
    const int b = t >> 5;          // image 0..7 (group of 32 threads)
    const int j = t & 31;
    float c = 0.f, r = 0.f, p = 0.f;
    for (int i = j; i < NBLK_X; i += 32) {
        const int idx = b * NBLK_X + i;
        c += part[idx];
        r += part[PLANE + idx];
        p += part[2 * PLANE + idx];
    }
    #pragma unroll
    for (int off = 16; off > 0; off >>= 1) {
        c += __shfl_down(c, off, 32);
        r += __shfl_down(r, off, 32);
        p += __shfl_down(p, off, 32);
    }
    __shared__ float s[B_IMG][3];
    if (j == 0) { s[b][0] = c; s[b][1] = r; s[b][2] = p; }
    __syncthreads();
    if (t == 0) {
        float cl = 0.f, rl = 0.f;
        #pragma unroll
        for (int bb = 0; bb < B_IMG; ++bb) {
            const float np  = s[bb][2];
            const float mnp = fmaxf(np, 1.0f);
            cl += s[bb][0] / mnp;
            rl += (np > 0.0f) ? s[bb][1] / (4.0f * mnp) : 0.0f;
        }
        out[0] = cl / (float)B_IMG;
        out[1] = rl / (float)B_IMG;
    }
}

extern "C" void kernel_launch(void* const* d_in, const int* in_sizes, int n_in,
                              void* d_out, int out_size, void* d_ws, size_t ws_size,
                              hipStream_t stream) {
    const float* cls     = (const float*)d_in[0];  // [B,A,C]
    const float* regr    = (const float*)d_in[1];  // [B,A,4]
    const float* anchors = (const float*)d_in[2];  // [1,A,4]
    const float* ann     = (const float*)d_in[3];  // [B,M,6]
    float* out  = (float*)d_out;
    float* part = (float*)d_ws;

    dim3 grid(NBLK_X, B_IMG);
    focal_main<<<grid, NTHREADS, 0, stream>>>(cls, regr, anchors, ann, part);
    focal_reduce<<<1, 256, 0, stream>>>(part, out);
}